// Round 10
// baseline (1152.004 us; speedup 1.0000x reference)
//
#include <hip/hip_runtime.h>
#include <stdint.h>

typedef signed char i8;
typedef unsigned char u8;
typedef __attribute__((ext_vector_type(4))) int i32x4;

__device__ __forceinline__ void gload_lds16(const void* g, void* l) {
  __builtin_amdgcn_global_load_lds(
      (__attribute__((address_space(1))) void*)const_cast<void*>(g),
      (__attribute__((address_space(3))) void*)l, 16, 0, 0);
}

// ---------- prep: per-row absmax quant of x (f32 [rows][4096] -> i8 + scale) ----------
__global__ __launch_bounds__(256) void k_quant_x(const float* __restrict__ in,
                                                 i8* __restrict__ out,
                                                 float* __restrict__ scale) {
  const int row = blockIdx.x, t = threadIdx.x;
  const float* src = in + (size_t)row * 4096;
  float4 v[4];
  float m = 0.f;
#pragma unroll
  for (int j = 0; j < 4; ++j) {
    v[j] = *(const float4*)(src + j * 1024 + t * 4);
    m = fmaxf(m, fmaxf(fmaxf(fabsf(v[j].x), fabsf(v[j].y)),
                       fmaxf(fabsf(v[j].z), fabsf(v[j].w))));
  }
#pragma unroll
  for (int off = 32; off; off >>= 1) m = fmaxf(m, __shfl_xor(m, off));
  __shared__ float wmax[4];
  if ((t & 63) == 0) wmax[t >> 6] = m;
  __syncthreads();
  m = fmaxf(fmaxf(wmax[0], wmax[1]), fmaxf(wmax[2], wmax[3]));
  const float inv = m > 0.f ? 127.f / m : 0.f;
  if (t == 0) scale[row] = m / 127.f;
#pragma unroll
  for (int j = 0; j < 4; ++j) {
    int q0 = (int)rintf(fmaxf(fminf(v[j].x * inv, 127.f), -127.f));
    int q1 = (int)rintf(fmaxf(fminf(v[j].y * inv, 127.f), -127.f));
    int q2 = (int)rintf(fmaxf(fminf(v[j].z * inv, 127.f), -127.f));
    int q3 = (int)rintf(fmaxf(fminf(v[j].w * inv, 127.f), -127.f));
    uint32_t p = (q0 & 255) | ((q1 & 255) << 8) | ((q2 & 255) << 16) | ((q3 & 255) << 24);
    *(uint32_t*)(out + (size_t)row * 4096 + j * 1024 + t * 4) = p;
  }
}

// ---------- prep: W' = W + 4*B@A, per-row quant to i8 + scale ----------
__global__ __launch_bounds__(256) void k_quant_w(const float* __restrict__ W,
                                                 const float* __restrict__ Am,
                                                 const float* __restrict__ Bm,
                                                 i8* __restrict__ out,
                                                 float* __restrict__ scale) {
  const int o = blockIdx.x, t = threadIdx.x;
  const float4 b4 = *(const float4*)(Bm + (o << 2));
  float4 v[4];
  float m = 0.f;
#pragma unroll
  for (int j = 0; j < 4; ++j) {
    const int i = j * 1024 + t * 4;
    float4 w  = *(const float4*)(W + ((size_t)o << 12) + i);
    float4 a0 = *(const float4*)(Am + i);
    float4 a1 = *(const float4*)(Am + 4096 + i);
    float4 a2 = *(const float4*)(Am + 8192 + i);
    float4 a3 = *(const float4*)(Am + 12288 + i);
    w.x += 4.f * (b4.x * a0.x + b4.y * a1.x + b4.z * a2.x + b4.w * a3.x);
    w.y += 4.f * (b4.x * a0.y + b4.y * a1.y + b4.z * a2.y + b4.w * a3.y);
    w.z += 4.f * (b4.x * a0.z + b4.y * a1.z + b4.z * a2.z + b4.w * a3.z);
    w.w += 4.f * (b4.x * a0.w + b4.y * a1.w + b4.z * a2.w + b4.w * a3.w);
    v[j] = w;
    m = fmaxf(m, fmaxf(fmaxf(fabsf(w.x), fabsf(w.y)), fmaxf(fabsf(w.z), fabsf(w.w))));
  }
#pragma unroll
  for (int off = 32; off; off >>= 1) m = fmaxf(m, __shfl_xor(m, off));
  __shared__ float wmax[4];
  if ((t & 63) == 0) wmax[t >> 6] = m;
  __syncthreads();
  m = fmaxf(fmaxf(wmax[0], wmax[1]), fmaxf(wmax[2], wmax[3]));
  const float inv = m > 0.f ? 127.f / m : 0.f;
  if (t == 0) scale[o] = m / 127.f;
#pragma unroll
  for (int j = 0; j < 4; ++j) {
    int q0 = (int)rintf(fmaxf(fminf(v[j].x * inv, 127.f), -127.f));
    int q1 = (int)rintf(fmaxf(fminf(v[j].y * inv, 127.f), -127.f));
    int q2 = (int)rintf(fmaxf(fminf(v[j].z * inv, 127.f), -127.f));
    int q3 = (int)rintf(fmaxf(fminf(v[j].w * inv, 127.f), -127.f));
    uint32_t p = (q0 & 255) | ((q1 & 255) << 8) | ((q2 & 255) << 16) | ((q3 & 255) << 24);
    *(uint32_t*)(out + (size_t)o * 4096 + j * 1024 + t * 4) = p;
  }
}

// ===== i8 GEMM, BK=64 (LDS 64 KiB -> 2 blocks/CU for inter-block overlap) =====
// C[m][n] = sx[m]*sw[n] * sum_k Aq[m][k]*Bq[n][k].  256x256 tile, 8 waves
// (interleaved mapping: A row = mh*128 + wr*64 + f*16 + l4, B row = nh*128 +
// wc*32 + g*16 + l4), double-buffered, 2 phases/K-tile.
// Counted-vmcnt chain (per-wave loads, 1 gload per half-tile, order A0,B0,B1,A1):
//   prologue vmcnt(1) -> A0,B0,B1 landed
//   ph-a end vmcnt(2) -> A1(t) landed (read in ph-b)   [tail: vmcnt(0)]
//   ph-b end vmcnt(1) -> A0,B0,B1(t+1) landed          [tail: skip]
// Swizzle for 64-B rows: store logical chunk c of row r at phys c ^ ((r>>1)&3);
// bank audit: each 16-lane q-group covers all 8 bank-groups exactly 2x (free).
__global__ __launch_bounds__(512, 4) void k_gq8(const u8* __restrict__ Ag,
                                                const u8* __restrict__ Bg,
                                                const float* __restrict__ sx,
                                                const float* __restrict__ sw,
                                                float* __restrict__ C,
                                                int M, int N, int K) {
  __shared__ __attribute__((aligned(16))) u8 As[2 * 16384];
  __shared__ __attribute__((aligned(16))) u8 Bs[2 * 16384];
  const int tid  = threadIdx.x;
  const int wave = tid >> 6, lane = tid & 63;
  const int wr = wave >> 2, wc = wave & 3;
  const int m0 = blockIdx.y * 256, n0 = blockIdx.x * 256;
  const int NT = K >> 6;                           // 64-byte K-tiles

  // staging: half-tile = 128 rows x 64 B = 8 KB = 512 lanes x 16 B = 1 gload
  const int srow = tid >> 2;                       // 0..127
  const int csrc = (tid & 3) ^ ((tid >> 3) & 3);   // pre-swizzled source chunk
  const u8* pA = Ag + (size_t)(m0 + srow) * K + csrc * 16;
  const u8* pB = Bg + (size_t)(n0 + srow) * K + csrc * 16;
  const size_t KH = (size_t)128 * K;               // half stride (rows)
  const int wb = wave << 10;                       // per-wave dest base (1 KB)

#define SA(nb, h, kt) gload_lds16(pA + (h) * KH + (kt), As + (nb) * 16384 + (h) * 8192 + wb)
#define SB(nb, h, kt) gload_lds16(pB + (h) * KH + (kt), Bs + (nb) * 16384 + (h) * 8192 + wb)

  // fragment reads: row 64 B; phys chunk = q ^ ((l4>>1)&3)
  const int l4 = lane & 15, q = lane >> 4;
  const int ke0 = (q ^ ((l4 >> 1) & 3)) << 4;      // byte offset within row
  const int aoff = ((wr << 6) + l4) << 6;          // (wr*64 + l4) * 64
  const int boff = ((wc << 5) + l4) << 6;          // (wc*32 + l4) * 64

  i32x4 acc[8][4] = {};
  i32x4 ar[4];         // current A-half [f]
  i32x4 bq[2][2];      // both B-halves [nh][g]

#define LDA(buf, mh)                                                           \
  do {                                                                         \
    const u8* b_ = As + (buf) * 16384 + (mh) * 8192 + aoff;                    \
    _Pragma("unroll") for (int f = 0; f < 4; ++f)                              \
      ar[f] = *(const i32x4*)(b_ + f * 1024 + ke0);                            \
  } while (0)
#define LDB(buf, nh)                                                           \
  do {                                                                         \
    const u8* b_ = Bs + (buf) * 16384 + (nh) * 8192 + boff;                    \
    _Pragma("unroll") for (int g = 0; g < 2; ++g)                              \
      bq[nh][g] = *(const i32x4*)(b_ + g * 1024 + ke0);                        \
  } while (0)
#define MFMA8(mh, nh)                                                          \
  do {                                                                         \
    _Pragma("unroll") for (int f = 0; f < 4; ++f)                              \
      _Pragma("unroll") for (int g = 0; g < 2; ++g)                            \
        acc[(mh) * 4 + f][(nh) * 2 + g] =                                      \
            __builtin_amdgcn_mfma_i32_16x16x64_i8(                             \
                ar[f], bq[nh][g], acc[(mh) * 4 + f][(nh) * 2 + g], 0, 0, 0);   \
  } while (0)

  // prologue: stage tile 0, order A0,B0,B1,A1
  SA(0, 0, 0);
  SB(0, 0, 0);
  SB(0, 1, 0);
  SA(0, 1, 0);
  asm volatile("s_waitcnt vmcnt(1)" ::: "memory");   // A0,B0,B1 landed
  __builtin_amdgcn_s_barrier();

  for (int t = 0; t < NT; ++t) {
    const int buf = t & 1, nb = buf ^ 1;
    const int kt1 = (t + 1) << 6;
    const bool st = (t + 1) < NT;

    // ---- ph-a: quadrants (0,0),(0,1); reads A0(4)+B0(2)+B1(2); stages A0,B0(t+1) ----
    LDA(buf, 0);
    LDB(buf, 0);
    LDB(buf, 1);
    if (st) { SA(nb, 0, kt1); SB(nb, 0, kt1); }
    asm volatile("s_waitcnt lgkmcnt(4)" ::: "memory");   // pacing
    __builtin_amdgcn_s_barrier();
    asm volatile("s_waitcnt lgkmcnt(0)" ::: "memory");
    __builtin_amdgcn_s_setprio(1);
    MFMA8(0, 0);
    MFMA8(0, 1);
    __builtin_amdgcn_s_setprio(0);
    if (st) { asm volatile("s_waitcnt vmcnt(2)" ::: "memory"); }
    else    { asm volatile("s_waitcnt vmcnt(0)" ::: "memory"); }
    __builtin_amdgcn_s_barrier();

    // ---- ph-b: quadrants (1,1),(1,0); reads A1(4); stages B1,A1(t+1) ----
    LDA(buf, 1);
    if (st) { SB(nb, 1, kt1); SA(nb, 1, kt1); }
    __builtin_amdgcn_s_barrier();
    asm volatile("s_waitcnt lgkmcnt(0)" ::: "memory");
    __builtin_amdgcn_s_setprio(1);
    MFMA8(1, 1);
    MFMA8(1, 0);
    __builtin_amdgcn_s_setprio(0);
    if (st) { asm volatile("s_waitcnt vmcnt(1)" ::: "memory"); }
    __builtin_amdgcn_s_barrier();
  }

  // epilogue: C/D col = lane&15, row = (lane>>4)*4 + reg (dtype-independent)
  float swv[4];
#pragma unroll
  for (int j = 0; j < 4; ++j)
    swv[j] = sw[n0 + (j >> 1) * 128 + wc * 32 + (j & 1) * 16 + l4];
#pragma unroll
  for (int i = 0; i < 8; ++i) {
    const int mh = i >> 2, f = i & 3;
    const int row = m0 + mh * 128 + wr * 64 + f * 16 + q * 4;
#pragma unroll
    for (int j = 0; j < 4; ++j) {
      const int nh = j >> 1, g = j & 1;
      const int col = n0 + nh * 128 + wc * 32 + g * 16 + l4;
#pragma unroll
      for (int v = 0; v < 4; ++v)
        C[(size_t)(row + v) * N + col] = (float)acc[i][j][v] * sx[row + v] * swv[j];
    }
  }
#undef SA
#undef SB
#undef LDA
#undef LDB
#undef MFMA8
}

// ---------------- fallback (generic shapes / no workspace): fp32 tiled ----------------
__global__ __launch_bounds__(256) void k_fallback(const float* __restrict__ X,
                                                  const float* __restrict__ W,
                                                  const float* __restrict__ Am,
                                                  const float* __restrict__ Bm,
                                                  float* __restrict__ C,
                                                  int M, int N, int K) {
  __shared__ float Xs[64][16];
  __shared__ float Ws[64][17];
  const int tid = threadIdx.x;
  const int tn = tid & 15, tm = tid >> 4;
  const int m0 = blockIdx.y * 64, n0 = blockIdx.x * 64;
  float acc[4][4] = {};
  for (int kt = 0; kt < K; kt += 16) {
    __syncthreads();
#pragma unroll
    for (int qq = 0; qq < 4; ++qq) {
      int idx = qq * 256 + tid;
      int r = idx >> 4, c = idx & 15;
      Xs[r][c] = X[(size_t)(m0 + r) * K + kt + c];
      float w = W[(size_t)(n0 + r) * K + kt + c];
      float4 b = *(const float4*)(Bm + ((n0 + r) << 2));
      w += 4.f * (b.x * Am[kt + c] + b.y * Am[4096 + kt + c] +
                  b.z * Am[8192 + kt + c] + b.w * Am[12288 + kt + c]);
      Ws[r][c] = w;
    }
    __syncthreads();
#pragma unroll
    for (int k = 0; k < 16; ++k) {
      float xv[4], wv[4];
#pragma unroll
      for (int i = 0; i < 4; ++i) xv[i] = Xs[tm * 4 + i][k];
#pragma unroll
      for (int j = 0; j < 4; ++j) wv[j] = Ws[tn * 4 + j][k];
#pragma unroll
      for (int i = 0; i < 4; ++i)
#pragma unroll
        for (int j = 0; j < 4; ++j) acc[i][j] += xv[i] * wv[j];
    }
  }
#pragma unroll
  for (int i = 0; i < 4; ++i)
#pragma unroll
    for (int j = 0; j < 4; ++j)
      C[(size_t)(m0 + tm * 4 + i) * N + n0 + tn * 4 + j] = acc[i][j];
}

extern "C" void kernel_launch(void* const* d_in, const int* in_sizes, int n_in,
                              void* d_out, int out_size, void* d_ws, size_t ws_size,
                              hipStream_t stream) {
  const float* x  = (const float*)d_in[0];
  const float* W  = (const float*)d_in[1];
  const float* lA = (const float*)d_in[2];
  const float* lB = (const float*)d_in[3];
  float* out = (float*)d_out;
  const int K = 4096, N = 4096;
  const int M = in_sizes[0] / K;   // 8192
  const size_t need = (size_t)(M + N) * K + (size_t)(M + N) * sizeof(float);

  if (ws_size >= need && (M % 256) == 0) {
    i8* xb = (i8*)d_ws;
    i8* wb = xb + (size_t)M * K;
    float* sx = (float*)(wb + (size_t)N * K);
    float* sw = sx + M;
    k_quant_x<<<dim3(M), dim3(256), 0, stream>>>(x, xb, sx);
    k_quant_w<<<dim3(N), dim3(256), 0, stream>>>(W, lA, lB, wb, sw);
    k_gq8<<<dim3(N / 256, M / 256), dim3(512), 0, stream>>>(
        (const u8*)xb, (const u8*)wb, sx, sw, out, M, N, K);
  } else {
    k_fallback<<<dim3(N / 64, M / 64), dim3(256), 0, stream>>>(x, W, lA, lB, out, M, N, K);
  }
}

// Round 11
// 208.485 us; speedup vs baseline: 5.5256x; 5.5256x over previous
//
#include <hip/hip_runtime.h>
#include <stdint.h>

typedef signed char i8;
typedef unsigned char u8;
typedef __attribute__((ext_vector_type(4))) int i32x4;

__device__ __forceinline__ void gload_lds16(const void* g, void* l) {
  __builtin_amdgcn_global_load_lds(
      (__attribute__((address_space(1))) void*)const_cast<void*>(g),
      (__attribute__((address_space(3))) void*)l, 16, 0, 0);
}

// ---------- prep: per-row absmax quant of x (f32 [rows][4096] -> i8 + scale) ----------
__global__ __launch_bounds__(256) void k_quant_x(const float* __restrict__ in,
                                                 i8* __restrict__ out,
                                                 float* __restrict__ scale) {
  const int row = blockIdx.x, t = threadIdx.x;
  const float* src = in + (size_t)row * 4096;
  float4 v[4];
  float m = 0.f;
#pragma unroll
  for (int j = 0; j < 4; ++j) {
    v[j] = *(const float4*)(src + j * 1024 + t * 4);
    m = fmaxf(m, fmaxf(fmaxf(fabsf(v[j].x), fabsf(v[j].y)),
                       fmaxf(fabsf(v[j].z), fabsf(v[j].w))));
  }
#pragma unroll
  for (int off = 32; off; off >>= 1) m = fmaxf(m, __shfl_xor(m, off));
  __shared__ float wmax[4];
  if ((t & 63) == 0) wmax[t >> 6] = m;
  __syncthreads();
  m = fmaxf(fmaxf(wmax[0], wmax[1]), fmaxf(wmax[2], wmax[3]));
  const float inv = m > 0.f ? 127.f / m : 0.f;
  if (t == 0) scale[row] = m / 127.f;
#pragma unroll
  for (int j = 0; j < 4; ++j) {
    int q0 = (int)rintf(fmaxf(fminf(v[j].x * inv, 127.f), -127.f));
    int q1 = (int)rintf(fmaxf(fminf(v[j].y * inv, 127.f), -127.f));
    int q2 = (int)rintf(fmaxf(fminf(v[j].z * inv, 127.f), -127.f));
    int q3 = (int)rintf(fmaxf(fminf(v[j].w * inv, 127.f), -127.f));
    uint32_t p = (q0 & 255) | ((q1 & 255) << 8) | ((q2 & 255) << 16) | ((q3 & 255) << 24);
    *(uint32_t*)(out + (size_t)row * 4096 + j * 1024 + t * 4) = p;
  }
}

// ---------- prep: W' = W + 4*B@A, per-row quant to i8 + scale ----------
__global__ __launch_bounds__(256) void k_quant_w(const float* __restrict__ W,
                                                 const float* __restrict__ Am,
                                                 const float* __restrict__ Bm,
                                                 i8* __restrict__ out,
                                                 float* __restrict__ scale) {
  const int o = blockIdx.x, t = threadIdx.x;
  const float4 b4 = *(const float4*)(Bm + (o << 2));
  float4 v[4];
  float m = 0.f;
#pragma unroll
  for (int j = 0; j < 4; ++j) {
    const int i = j * 1024 + t * 4;
    float4 w  = *(const float4*)(W + ((size_t)o << 12) + i);
    float4 a0 = *(const float4*)(Am + i);
    float4 a1 = *(const float4*)(Am + 4096 + i);
    float4 a2 = *(const float4*)(Am + 8192 + i);
    float4 a3 = *(const float4*)(Am + 12288 + i);
    w.x += 4.f * (b4.x * a0.x + b4.y * a1.x + b4.z * a2.x + b4.w * a3.x);
    w.y += 4.f * (b4.x * a0.y + b4.y * a1.y + b4.z * a2.y + b4.w * a3.y);
    w.z += 4.f * (b4.x * a0.z + b4.y * a1.z + b4.z * a2.z + b4.w * a3.z);
    w.w += 4.f * (b4.x * a0.w + b4.y * a1.w + b4.z * a2.w + b4.w * a3.w);
    v[j] = w;
    m = fmaxf(m, fmaxf(fmaxf(fabsf(w.x), fabsf(w.y)), fmaxf(fabsf(w.z), fabsf(w.w))));
  }
#pragma unroll
  for (int off = 32; off; off >>= 1) m = fmaxf(m, __shfl_xor(m, off));
  __shared__ float wmax[4];
  if ((t & 63) == 0) wmax[t >> 6] = m;
  __syncthreads();
  m = fmaxf(fmaxf(wmax[0], wmax[1]), fmaxf(wmax[2], wmax[3]));
  const float inv = m > 0.f ? 127.f / m : 0.f;
  if (t == 0) scale[o] = m / 127.f;
#pragma unroll
  for (int j = 0; j < 4; ++j) {
    int q0 = (int)rintf(fmaxf(fminf(v[j].x * inv, 127.f), -127.f));
    int q1 = (int)rintf(fmaxf(fminf(v[j].y * inv, 127.f), -127.f));
    int q2 = (int)rintf(fmaxf(fminf(v[j].z * inv, 127.f), -127.f));
    int q3 = (int)rintf(fmaxf(fminf(v[j].w * inv, 127.f), -127.f));
    uint32_t p = (q0 & 255) | ((q1 & 255) << 8) | ((q2 & 255) << 16) | ((q3 & 255) << 24);
    *(uint32_t*)(out + (size_t)o * 4096 + j * 1024 + t * 4) = p;
  }
}

// ===== i8 GEMM, BK=64, LDS 64 KiB; launch_bounds(512,2) so VGPR ~116 (no spill)
// and the HW can still co-schedule 2 blocks/CU (16 waves/CU, VGPR pool fits).
// Structure identical to R10 otherwise (R9 phases at BK=64, counted vmcnt).
__global__ __launch_bounds__(512, 2) void k_gq8(const u8* __restrict__ Ag,
                                                const u8* __restrict__ Bg,
                                                const float* __restrict__ sx,
                                                const float* __restrict__ sw,
                                                float* __restrict__ C,
                                                int M, int N, int K) {
  __shared__ __attribute__((aligned(16))) u8 As[2 * 16384];
  __shared__ __attribute__((aligned(16))) u8 Bs[2 * 16384];
  const int tid  = threadIdx.x;
  const int wave = tid >> 6, lane = tid & 63;
  const int wr = wave >> 2, wc = wave & 3;
  const int m0 = blockIdx.y * 256, n0 = blockIdx.x * 256;
  const int NT = K >> 6;                           // 64-byte K-tiles

  // staging: half-tile = 128 rows x 64 B = 8 KB = 512 lanes x 16 B = 1 gload
  const int srow = tid >> 2;                       // 0..127
  const int csrc = (tid & 3) ^ ((tid >> 3) & 3);   // pre-swizzled source chunk
  const u8* pA = Ag + (size_t)(m0 + srow) * K + csrc * 16;
  const u8* pB = Bg + (size_t)(n0 + srow) * K + csrc * 16;
  const size_t KH = (size_t)128 * K;               // half stride (rows)
  const int wb = wave << 10;                       // per-wave dest base (1 KB)

#define SA(nb, h, kt) gload_lds16(pA + (h) * KH + (kt), As + (nb) * 16384 + (h) * 8192 + wb)
#define SB(nb, h, kt) gload_lds16(pB + (h) * KH + (kt), Bs + (nb) * 16384 + (h) * 8192 + wb)

  // fragment reads: row 64 B; phys chunk = q ^ ((l4>>1)&3)
  const int l4 = lane & 15, q = lane >> 4;
  const int ke0 = (q ^ ((l4 >> 1) & 3)) << 4;      // byte offset within row
  const int aoff = ((wr << 6) + l4) << 6;          // (wr*64 + l4) * 64
  const int boff = ((wc << 5) + l4) << 6;          // (wc*32 + l4) * 64

  i32x4 acc[8][4] = {};
  i32x4 ar[4];         // current A-half [f]
  i32x4 bq[2][2];      // both B-halves [nh][g]

#define LDA(buf, mh)                                                           \
  do {                                                                         \
    const u8* b_ = As + (buf) * 16384 + (mh) * 8192 + aoff;                    \
    _Pragma("unroll") for (int f = 0; f < 4; ++f)                              \
      ar[f] = *(const i32x4*)(b_ + f * 1024 + ke0);                            \
  } while (0)
#define LDB(buf, nh)                                                           \
  do {                                                                         \
    const u8* b_ = Bs + (buf) * 16384 + (nh) * 8192 + boff;                    \
    _Pragma("unroll") for (int g = 0; g < 2; ++g)                              \
      bq[nh][g] = *(const i32x4*)(b_ + g * 1024 + ke0);                        \
  } while (0)
#define MFMA8(mh, nh)                                                          \
  do {                                                                         \
    _Pragma("unroll") for (int f = 0; f < 4; ++f)                              \
      _Pragma("unroll") for (int g = 0; g < 2; ++g)                            \
        acc[(mh) * 4 + f][(nh) * 2 + g] =                                      \
            __builtin_amdgcn_mfma_i32_16x16x64_i8(                             \
                ar[f], bq[nh][g], acc[(mh) * 4 + f][(nh) * 2 + g], 0, 0, 0);   \
  } while (0)

  // prologue: stage tile 0, order A0,B0,B1,A1
  SA(0, 0, 0);
  SB(0, 0, 0);
  SB(0, 1, 0);
  SA(0, 1, 0);
  asm volatile("s_waitcnt vmcnt(1)" ::: "memory");   // A0,B0,B1 landed
  __builtin_amdgcn_s_barrier();

  for (int t = 0; t < NT; ++t) {
    const int buf = t & 1, nb = buf ^ 1;
    const int kt1 = (t + 1) << 6;
    const bool st = (t + 1) < NT;

    // ---- ph-a: quadrants (0,0),(0,1); reads A0(4)+B0(2)+B1(2); stages A0,B0(t+1) ----
    LDA(buf, 0);
    LDB(buf, 0);
    LDB(buf, 1);
    if (st) { SA(nb, 0, kt1); SB(nb, 0, kt1); }
    asm volatile("s_waitcnt lgkmcnt(4)" ::: "memory");   // pacing
    __builtin_amdgcn_s_barrier();
    asm volatile("s_waitcnt lgkmcnt(0)" ::: "memory");
    __builtin_amdgcn_s_setprio(1);
    MFMA8(0, 0);
    MFMA8(0, 1);
    __builtin_amdgcn_s_setprio(0);
    if (st) { asm volatile("s_waitcnt vmcnt(2)" ::: "memory"); }
    else    { asm volatile("s_waitcnt vmcnt(0)" ::: "memory"); }
    __builtin_amdgcn_s_barrier();

    // ---- ph-b: quadrants (1,1),(1,0); reads A1(4); stages B1,A1(t+1) ----
    LDA(buf, 1);
    if (st) { SB(nb, 1, kt1); SA(nb, 1, kt1); }
    __builtin_amdgcn_s_barrier();
    asm volatile("s_waitcnt lgkmcnt(0)" ::: "memory");
    __builtin_amdgcn_s_setprio(1);
    MFMA8(1, 1);
    MFMA8(1, 0);
    __builtin_amdgcn_s_setprio(0);
    if (st) { asm volatile("s_waitcnt vmcnt(1)" ::: "memory"); }
    __builtin_amdgcn_s_barrier();
  }

  // epilogue: C/D col = lane&15, row = (lane>>4)*4 + reg (dtype-independent)
  float swv[4];
#pragma unroll
  for (int j = 0; j < 4; ++j)
    swv[j] = sw[n0 + (j >> 1) * 128 + wc * 32 + (j & 1) * 16 + l4];
#pragma unroll
  for (int i = 0; i < 8; ++i) {
    const int mh = i >> 2, f = i & 3;
    const int row = m0 + mh * 128 + wr * 64 + f * 16 + q * 4;
#pragma unroll
    for (int j = 0; j < 4; ++j) {
      const int nh = j >> 1, g = j & 1;
      const int col = n0 + nh * 128 + wc * 32 + g * 16 + l4;
#pragma unroll
      for (int v = 0; v < 4; ++v)
        C[(size_t)(row + v) * N + col] = (float)acc[i][j][v] * sx[row + v] * swv[j];
    }
  }
#undef SA
#undef SB
#undef LDA
#undef LDB
#undef MFMA8
}

// ---------------- fallback (generic shapes / no workspace): fp32 tiled ----------------
__global__ __launch_bounds__(256) void k_fallback(const float* __restrict__ X,
                                                  const float* __restrict__ W,
                                                  const float* __restrict__ Am,
                                                  const float* __restrict__ Bm,
                                                  float* __restrict__ C,
                                                  int M, int N, int K) {
  __shared__ float Xs[64][16];
  __shared__ float Ws[64][17];
  const int tid = threadIdx.x;
  const int tn = tid & 15, tm = tid >> 4;
  const int m0 = blockIdx.y * 64, n0 = blockIdx.x * 64;
  float acc[4][4] = {};
  for (int kt = 0; kt < K; kt += 16) {
    __syncthreads();
#pragma unroll
    for (int qq = 0; qq < 4; ++qq) {
      int idx = qq * 256 + tid;
      int r = idx >> 4, c = idx & 15;
      Xs[r][c] = X[(size_t)(m0 + r) * K + kt + c];
      float w = W[(size_t)(n0 + r) * K + kt + c];
      float4 b = *(const float4*)(Bm + ((n0 + r) << 2));
      w += 4.f * (b.x * Am[kt + c] + b.y * Am[4096 + kt + c] +
                  b.z * Am[8192 + kt + c] + b.w * Am[12288 + kt + c]);
      Ws[r][c] = w;
    }
    __syncthreads();
#pragma unroll
    for (int k = 0; k < 16; ++k) {
      float xv[4], wv[4];
#pragma unroll
      for (int i = 0; i < 4; ++i) xv[i] = Xs[tm * 4 + i][k];
#pragma unroll
      for (int j = 0; j < 4; ++j) wv[j] = Ws[tn * 4 + j][k];
#pragma unroll
      for (int i = 0; i < 4; ++i)
#pragma unroll
        for (int j = 0; j < 4; ++j) acc[i][j] += xv[i] * wv[j];
    }
  }
#pragma unroll
  for (int i = 0; i < 4; ++i)
#pragma unroll
    for (int j = 0; j < 4; ++j)
      C[(size_t)(m0 + tm * 4 + i) * N + n0 + tn * 4 + j] = acc[i][j];
}

extern "C" void kernel_launch(void* const* d_in, const int* in_sizes, int n_in,
                              void* d_out, int out_size, void* d_ws, size_t ws_size,
                              hipStream_t stream) {
  const float* x  = (const float*)d_in[0];
  const float* W  = (const float*)d_in[1];
  const float* lA = (const float*)d_in[2];
  const float* lB = (const float*)d_in[3];
  float* out = (float*)d_out;
  const int K = 4096, N = 4096;
  const int M = in_sizes[0] / K;   // 8192
  const size_t need = (size_t)(M + N) * K + (size_t)(M + N) * sizeof(float);

  if (ws_size >= need && (M % 256) == 0) {
    i8* xb = (i8*)d_ws;
    i8* wb = xb + (size_t)M * K;
    float* sx = (float*)(wb + (size_t)N * K);
    float* sw = sx + M;
    k_quant_x<<<dim3(M), dim3(256), 0, stream>>>(x, xb, sx);
    k_quant_w<<<dim3(N), dim3(256), 0, stream>>>(W, lA, lB, wb, sw);
    k_gq8<<<dim3(N / 256, M / 256), dim3(512), 0, stream>>>(
        (const u8*)xb, (const u8*)wb, sx, sw, out, M, N, K);
  } else {
    k_fallback<<<dim3(N / 64, M / 64), dim3(256), 0, stream>>>(x, W, lA, lB, out, M, N, K);
  }
}